// Round 2
// baseline (76.622 us; speedup 1.0000x reference)
//
#include <hip/hip_runtime.h>
#include <hip/hip_bf16.h>

#define IN 8192
#define OUT 8192

typedef __bf16 bf16x8 __attribute__((ext_vector_type(8)));
typedef float f32x4 __attribute__((ext_vector_type(4)));
typedef unsigned short u16;

// ---------------- pre1: t[b,i,k] = sum_j v1[i,j] * (x[b,v_inp[j*128+k]] / shw[v_inp[...]]) ----------------
__global__ __launch_bounds__(256)
void pre1_kernel(const float* __restrict__ x, const float* __restrict__ shw,
                 const int* __restrict__ vinp, const float* __restrict__ v1,
                 float* __restrict__ t) {
    __shared__ float v1s[64][65];
    __shared__ float xs[64][17];
    const int kc = blockIdx.x, b = blockIdx.y, tid = threadIdx.x;
    for (int e = tid; e < 4096; e += 256) v1s[e >> 6][e & 63] = v1[e];
    for (int e = tid; e < 1024; e += 256) {
        int j = e >> 4, kk = e & 15;
        int gi = vinp[j * 128 + kc * 16 + kk];
        xs[j][kk] = x[b * IN + gi] / shw[gi];
    }
    __syncthreads();
    for (int e = tid; e < 1024; e += 256) {
        int i = e >> 4, kk = e & 15;
        float acc = 0.f;
        #pragma unroll
        for (int j = 0; j < 64; ++j) acc += v1s[i][j] * xs[j][kk];
        t[((size_t)b * 64 + i) * 128 + kc * 16 + kk] = acc;
    }
}

// ---------------- pre2: xt[b,p] = bf16( sum_k t[b, q>>7, k] * v2[q&127, k] ), q=v_outp[p]; Spart partials ----------------
__global__ __launch_bounds__(256)
void pre2_kernel(const float* __restrict__ t, const float* __restrict__ v2,
                 const int* __restrict__ voutp, __hip_bfloat16* __restrict__ xt,
                 float* __restrict__ Spart) {
    const int b = blockIdx.y, pc = blockIdx.x, tid = threadIdx.x;
    const int p = pc * 256 + tid;
    const int q = voutp[p];
    const int i = q >> 7, l = q & 127;
    const float* trow = t + ((size_t)b * 64 + i) * 128;
    const float* vrow = v2 + l * 128;
    float acc = 0.f;
    #pragma unroll
    for (int k = 0; k < 128; k += 4) {
        float4 tv = *(const float4*)(trow + k);
        float4 vv = *(const float4*)(vrow + k);
        acc += tv.x * vv.x + tv.y * vv.y + tv.z * vv.z + tv.w * vv.w;
    }
    __hip_bfloat16 hv = __float2bfloat16(acc);
    xt[(size_t)b * IN + p] = hv;
    float s = __bfloat162float(hv);
    #pragma unroll
    for (int off = 32; off; off >>= 1) s += __shfl_down(s, off, 64);
    __shared__ float wsum[4];
    if ((tid & 63) == 0) wsum[tid >> 6] = s;
    __syncthreads();
    if (tid == 0) Spart[b * 32 + pc] = (wsum[0] + wsum[1]) + (wsum[2] + wsum[3]);
}

// ---------------- main GEMM: G[plane][m][o] = sum_{k in plane} xt[m,k] * code(k,o) ----------------
__global__ __launch_bounds__(256)
void qgemm_kernel(const int* __restrict__ qw, const u16* __restrict__ xt,
                  float* __restrict__ G) {
    const int tid = threadIdx.x;
    const int lane = tid & 63;
    const int wave = tid >> 6;
    const int l15 = lane & 15;
    const int l4 = lane >> 4;
    const int o = blockIdx.x * 64 + wave * 16 + l15;       // output column
    const int k0 = blockIdx.y * 2048;                      // K-split plane start
    const int* qp = qw + (size_t)((k0 >> 3) + l4) * OUT + o;
    const u16* ap = xt + (size_t)l15 * IN + k0 + l4 * 8;
    f32x4 acc = {0.f, 0.f, 0.f, 0.f};
    #pragma unroll 4
    for (int kt = 0; kt < 64; ++kt) {
        unsigned int q = *(const unsigned int*)qp;
        bf16x8 a = __builtin_bit_cast(bf16x8, *(const uint4*)ap);
        u16 bb[8];
        #pragma unroll
        for (int s = 0; s < 8; ++s) {
            unsigned int c = (q >> (4 * s)) & 15u;
            float fv = __uint_as_float(0x4B000000u | c) - 8388608.0f;   // exact float(c)
            bb[s] = (u16)(__float_as_uint(fv) >> 16);                    // exact bf16(c)
        }
        bf16x8 bfrag;
        #pragma unroll
        for (int s = 0; s < 8; ++s) bfrag[s] = __builtin_bit_cast(__bf16, bb[s]);
        acc = __builtin_amdgcn_mfma_f32_16x16x32_bf16(a, bfrag, acc, 0, 0, 0);
        qp += 4 * OUT;
        ap += 32;
    }
    // D layout: col = lane&15, row = (lane>>4)*4 + r
    float* g = G + ((size_t)blockIdx.y * 16 + l4 * 4) * OUT + o;
    #pragma unroll
    for (int r = 0; r < 4; ++r) g[(size_t)r * OUT] = acc[r];
}

// ---------------- post1: t2[b,i,k] = sum_j u1[j,i] * og[b,j,k],
//    og[b,j,k] = scale[o]*( (2/15)*Gsum[b,o] - S[b] ), o = u_outp[j*128+k]. Also u2 transpose. ----------------
__global__ __launch_bounds__(256)
void post1_kernel(const float* __restrict__ G, const float* __restrict__ Spart,
                  const int* __restrict__ uoutp, const float* __restrict__ scale,
                  const float* __restrict__ u1, float* __restrict__ t2,
                  const float* __restrict__ u2, float* __restrict__ u2T) {
    __shared__ float u1s[64][65];
    __shared__ float og[64][17];
    const int kc = blockIdx.x, b = blockIdx.y, tid = threadIdx.x;
    // side job: transpose u2 (fp32 [k][l]) -> u2T (fp32 [l][k]) for post2's row-contiguous reads
    {
        int bb = b * 8 + kc;
        if (tid < 128) {
            int e = bb * 128 + tid;   // e = l*128 + k
            u2T[e] = u2[(e & 127) * 128 + (e >> 7)];
        }
    }
    float Sb = 0.f;
    #pragma unroll
    for (int c = 0; c < 32; ++c) Sb += Spart[b * 32 + c];
    for (int e = tid; e < 4096; e += 256) u1s[e >> 6][e & 63] = u1[e];
    for (int e = tid; e < 1024; e += 256) {
        int j = e >> 4, kk = e & 15;
        int o = uoutp[j * 128 + kc * 16 + kk];
        float g = 0.f;
        #pragma unroll
        for (int pl = 0; pl < 4; ++pl) g += G[((size_t)pl * 16 + b) * OUT + o];
        og[j][kk] = scale[o] * (g * (2.0f / 15.0f) - Sb);
    }
    __syncthreads();
    for (int e = tid; e < 1024; e += 256) {
        int i = e >> 4, kk = e & 15;
        float acc = 0.f;
        #pragma unroll
        for (int j = 0; j < 64; ++j) acc += u1s[j][i] * og[j][kk];
        t2[((size_t)b * 64 + i) * 128 + kc * 16 + kk] = acc;
    }
}

// ---------------- post2: out[b,p] = sum_k t2[b, q>>7, k]*u2T[q&127, k] + bias[p], q=u_inp[p] ----------------
__global__ __launch_bounds__(256)
void post2_kernel(const float* __restrict__ t2, const float* __restrict__ u2T,
                  const int* __restrict__ uinp, const float* __restrict__ bias,
                  float* __restrict__ out) {
    const int b = blockIdx.y, pc = blockIdx.x, tid = threadIdx.x;
    const int p = pc * 256 + tid;
    const int q = uinp[p];
    const int i = q >> 7, l = q & 127;
    const float* trow = t2 + ((size_t)b * 64 + i) * 128;
    const float* urow = u2T + l * 128;
    float acc = bias[p];
    #pragma unroll
    for (int k = 0; k < 128; k += 4) {
        float4 tv = *(const float4*)(trow + k);
        float4 uv = *(const float4*)(urow + k);
        acc += tv.x * uv.x + tv.y * uv.y + tv.z * uv.z + tv.w * uv.w;
    }
    out[(size_t)b * OUT + p] = acc;
}

extern "C" void kernel_launch(void* const* d_in, const int* in_sizes, int n_in,
                              void* d_out, int out_size, void* d_ws, size_t ws_size,
                              hipStream_t stream) {
    const float* x     = (const float*)d_in[0];
    const int*   qw    = (const int*)d_in[1];
    const float* scale = (const float*)d_in[2];
    const float* shw   = (const float*)d_in[3];
    const float* v1    = (const float*)d_in[4];
    const float* v2    = (const float*)d_in[5];
    const float* u1    = (const float*)d_in[6];
    const float* u2    = (const float*)d_in[7];
    const float* bias  = (const float*)d_in[8];
    const int* vinp  = (const int*)d_in[9];
    const int* voutp = (const int*)d_in[10];
    const int* uinp  = (const int*)d_in[11];
    const int* uoutp = (const int*)d_in[12];
    float* out = (float*)d_out;

    char* ws = (char*)d_ws;
    __hip_bfloat16* xt = (__hip_bfloat16*)(ws);               // 256 KiB  [16][8192] bf16
    float* t     = (float*)(ws + (256 << 10));                // 512 KiB  [16][64][128]
    float* G     = (float*)(ws + (768 << 10));                // 2 MiB    [4][16][8192]
    float* t2    = (float*)(ws + (2816 << 10));               // 512 KiB  [16][64][128]
    float* u2T   = (float*)(ws + (3328 << 10));               // 64 KiB   [128][128]
    float* Spart = (float*)(ws + (3392 << 10));               // 2 KiB    [16][32]

    pre1_kernel<<<dim3(8, 16), 256, 0, stream>>>(x, shw, vinp, v1, t);
    pre2_kernel<<<dim3(32, 16), 256, 0, stream>>>(t, v2, voutp, xt, Spart);
    qgemm_kernel<<<dim3(128, 4), 256, 0, stream>>>(qw, (const u16*)xt, G);
    post1_kernel<<<dim3(8, 16), 256, 0, stream>>>(G, Spart, uoutp, scale, u1, t2, u2, u2T);
    post2_kernel<<<dim3(32, 16), 256, 0, stream>>>(t2, u2T, uinp, bias, out);
}

// Round 3
// 53.399 us; speedup vs baseline: 1.4349x; 1.4349x over previous
//
#include <hip/hip_runtime.h>
#include <hip/hip_bf16.h>

#define IN 8192
#define OUT 8192

typedef __bf16 bf16x8 __attribute__((ext_vector_type(8)));
typedef float f32x4 __attribute__((ext_vector_type(4)));
typedef unsigned short u16;
typedef unsigned int u32;
typedef u32 u32x4 __attribute__((ext_vector_type(4)));

#define MFMA(a, b, c) __builtin_amdgcn_mfma_f32_16x16x32_bf16(a, b, c, 0, 0, 0)

static __device__ __forceinline__ u16 f2bf(float v) {
    __hip_bfloat16 h = __float2bfloat16(v);
    return __builtin_bit_cast(u16, h);
}
static __device__ __forceinline__ float bf2f(u16 h) {
    union { u32 u; float f; } cv; cv.u = ((u32)h) << 16; return cv.f;
}
static __device__ __forceinline__ void split_hl(float v, u16& hi, u16& lo) {
    hi = f2bf(v);
    lo = f2bf(v - bf2f(hi));
}
static __device__ __forceinline__ bf16x8 ld8(const u16* p) {
    return *reinterpret_cast<const bf16x8*>(p);
}

// ================= pre: butterfly-in + scatter to bf16 xt + S[b] =================
// per block b: X[j][n] = x[b, vinp[j*128+n]]/shw[...]; T = v1 @ X; Z = T @ v2^T;
// xt[b,p] = bf16(Z_flat[voutp[p]]); S[b] = sum_p bf16(Z).
__global__ __launch_bounds__(1024)
void pre_kernel(const float* __restrict__ x, const float* __restrict__ shw,
                const int* __restrict__ vinp, const int* __restrict__ voutp,
                const float* __restrict__ v1, const float* __restrict__ v2,
                u16* __restrict__ xt, float* __restrict__ S) {
    __shared__ alignas(16) u16 sV1[2][64 * 72];     // v1 hi/lo, [i][j] stride 72
    __shared__ alignas(16) u16 sXb[2][128 * 72];    // X^T [n][j] stride 72; reused as T [i][k] stride 136
    __shared__ alignas(16) u16 sV2[2][128 * 136];   // v2 [l][k] stride 136
    __shared__ float sred[16];
    const int tid = threadIdx.x, b = blockIdx.x;
    const int lane = tid & 63, w = tid >> 6;
    const int l15 = lane & 15, l4 = lane >> 4;

    #pragma unroll
    for (int it = 0; it < 4; ++it) {                // v1: 4096
        int e = tid + it * 1024;
        u16 h, l; split_hl(v1[e], h, l);
        int idx = (e >> 6) * 72 + (e & 63);
        sV1[0][idx] = h; sV1[1][idx] = l;
    }
    #pragma unroll
    for (int it = 0; it < 16; ++it) {               // v2: 16384, natural [l][k]
        int e = tid + it * 1024;
        u16 h, l; split_hl(v2[e], h, l);
        int idx = (e >> 7) * 136 + (e & 127);
        sV2[0][idx] = h; sV2[1][idx] = l;
    }
    int qidx[8];
    #pragma unroll
    for (int it = 0; it < 8; ++it) qidx[it] = vinp[tid + it * 1024];
    #pragma unroll
    for (int it = 0; it < 8; ++it) {                // X gather, store transposed [n][j]
        int q = qidx[it];
        float v = x[b * IN + q] / shw[q];
        u16 h, l; split_hl(v, h, l);
        int e = tid + it * 1024;
        int idx = (e & 127) * 72 + (e >> 7);
        sXb[0][idx] = h; sXb[1][idx] = l;
    }
    __syncthreads();

    // stage1: T = v1 @ X  (M=64,N=128,K=64). wave: n-tile nt, m-half mh.
    const int nt = w & 7, mh = w >> 3;
    f32x4 acc0 = {0.f, 0.f, 0.f, 0.f}, acc1 = {0.f, 0.f, 0.f, 0.f};
    #pragma unroll
    for (int ks = 0; ks < 2; ++ks) {
        int boff = (nt * 16 + l15) * 72 + ks * 32 + l4 * 8;
        bf16x8 bh = ld8(&sXb[0][boff]), bl = ld8(&sXb[1][boff]);
        int a0 = (mh * 32 + l15) * 72 + ks * 32 + l4 * 8;
        int a1 = a0 + 16 * 72;
        bf16x8 ah0 = ld8(&sV1[0][a0]), al0 = ld8(&sV1[1][a0]);
        bf16x8 ah1 = ld8(&sV1[0][a1]), al1 = ld8(&sV1[1][a1]);
        acc0 = MFMA(ah0, bh, acc0); acc0 = MFMA(ah0, bl, acc0); acc0 = MFMA(al0, bh, acc0);
        acc1 = MFMA(ah1, bh, acc1); acc1 = MFMA(ah1, bl, acc1); acc1 = MFMA(al1, bh, acc1);
    }
    __syncthreads();                                // all waves done reading sXb
    u16* Thi = sXb[0]; u16* Tlo = sXb[1];           // T [i][k] stride 136
    #pragma unroll
    for (int m = 0; m < 2; ++m) {
        f32x4 a = m ? acc1 : acc0;
        #pragma unroll
        for (int r = 0; r < 4; ++r) {
            int i = mh * 32 + m * 16 + l4 * 4 + r;
            u16 h, l; split_hl(a[r], h, l);
            Thi[i * 136 + nt * 16 + l15] = h;
            Tlo[i * 136 + nt * 16 + l15] = l;
        }
    }
    __syncthreads();

    // stage2: Z = T @ v2^T  (M=64,N=128,K=128)
    f32x4 z0 = {0.f, 0.f, 0.f, 0.f}, z1 = {0.f, 0.f, 0.f, 0.f};
    #pragma unroll
    for (int ks = 0; ks < 4; ++ks) {
        int boff = (nt * 16 + l15) * 136 + ks * 32 + l4 * 8;
        bf16x8 bh = ld8(&sV2[0][boff]), bl = ld8(&sV2[1][boff]);
        int a0 = (mh * 32 + l15) * 136 + ks * 32 + l4 * 8;
        int a1 = a0 + 16 * 136;
        bf16x8 ah0 = ld8(&Thi[a0]), al0 = ld8(&Tlo[a0]);
        bf16x8 ah1 = ld8(&Thi[a1]), al1 = ld8(&Tlo[a1]);
        z0 = MFMA(ah0, bh, z0); z0 = MFMA(ah0, bl, z0); z0 = MFMA(al0, bh, z0);
        z1 = MFMA(ah1, bh, z1); z1 = MFMA(ah1, bl, z1); z1 = MFMA(al1, bh, z1);
    }
    __syncthreads();
    u16* Zl = &sV1[0][0];                           // 8192 u16, reuse v1 region
    #pragma unroll
    for (int m = 0; m < 2; ++m) {
        f32x4 zz = m ? z1 : z0;
        #pragma unroll
        for (int r = 0; r < 4; ++r) {
            int i = mh * 32 + m * 16 + l4 * 4 + r;
            Zl[i * 128 + nt * 16 + l15] = f2bf(zz[r]);
        }
    }
    __syncthreads();
    float ssum = 0.f;
    #pragma unroll
    for (int it = 0; it < 8; ++it) {
        int p = tid + it * 1024;
        u16 zb = Zl[voutp[p]];
        xt[(size_t)b * IN + p] = zb;
        ssum += bf2f(zb);
    }
    #pragma unroll
    for (int off = 32; off; off >>= 1) ssum += __shfl_down(ssum, off, 64);
    if (lane == 0) sred[w] = ssum;
    __syncthreads();
    if (tid == 0) {
        float t = 0.f;
        #pragma unroll
        for (int i = 0; i < 16; ++i) t += sred[i];
        S[b] = t;
    }
}

// ================= qgemm: G[pl][b][o] = sum_{k in plane pl} xt[b,k]*code(k,o) =================
__global__ __launch_bounds__(256)
void qgemm_kernel(const int* __restrict__ qw, const u16* __restrict__ xt,
                  float* __restrict__ G) {
    __shared__ alignas(16) u16 sA[16 * 2056];       // xt tile [16][2048] padded +8
    const int tid = threadIdx.x;
    const int lane = tid & 63, w = tid >> 6;
    const int l15 = lane & 15, l4 = lane >> 4;
    const int k0 = blockIdx.y * 2048;
    #pragma unroll
    for (int i = 0; i < 16; ++i) {
        int idx = tid + i * 256;
        int r = idx >> 8, c = idx & 255;
        *reinterpret_cast<u32x4*>(&sA[r * 2056 + c * 8]) =
            *reinterpret_cast<const u32x4*>(&xt[(size_t)r * IN + k0 + c * 8]);
    }
    __syncthreads();
    const int o = blockIdx.x * 64 + w * 16 + l15;
    const int* qp = qw + (size_t)(k0 / 8 + l4) * OUT + o;
    f32x4 acc = {0.f, 0.f, 0.f, 0.f};
    #pragma unroll 8
    for (int kt = 0; kt < 64; ++kt) {
        u32 q = (u32)qp[(size_t)kt * 4 * OUT];
        bf16x8 a = ld8(&sA[l15 * 2056 + kt * 32 + l4 * 8]);
        u32 ev = q & 0x0F0F0F0Fu, od = (q >> 4) & 0x0F0F0F0Fu;
        float f0, f1, f2, f3, f4, f5, f6, f7;
        asm("v_cvt_f32_ubyte0 %0, %1" : "=v"(f0) : "v"(ev));
        asm("v_cvt_f32_ubyte0 %0, %1" : "=v"(f1) : "v"(od));
        asm("v_cvt_f32_ubyte1 %0, %1" : "=v"(f2) : "v"(ev));
        asm("v_cvt_f32_ubyte1 %0, %1" : "=v"(f3) : "v"(od));
        asm("v_cvt_f32_ubyte2 %0, %1" : "=v"(f4) : "v"(ev));
        asm("v_cvt_f32_ubyte2 %0, %1" : "=v"(f5) : "v"(od));
        asm("v_cvt_f32_ubyte3 %0, %1" : "=v"(f6) : "v"(ev));
        asm("v_cvt_f32_ubyte3 %0, %1" : "=v"(f7) : "v"(od));
        u32 p0, p1, p2, p3;
        asm("v_cvt_pk_bf16_f32 %0, %1, %2" : "=v"(p0) : "v"(f0), "v"(f1));
        asm("v_cvt_pk_bf16_f32 %0, %1, %2" : "=v"(p1) : "v"(f2), "v"(f3));
        asm("v_cvt_pk_bf16_f32 %0, %1, %2" : "=v"(p2) : "v"(f4), "v"(f5));
        asm("v_cvt_pk_bf16_f32 %0, %1, %2" : "=v"(p3) : "v"(f6), "v"(f7));
        u32x4 pk = {p0, p1, p2, p3};
        acc = MFMA(a, __builtin_bit_cast(bf16x8, pk), acc);
    }
    float* g = G + ((size_t)blockIdx.y * 16 + l4 * 4) * OUT + o;
    #pragma unroll
    for (int r = 0; r < 4; ++r) g[(size_t)r * OUT] = acc[r];
}

// ================= post: plane-reduce + scale/offset + butterfly-out + bias =================
// per block b: og[j][n] = scale[o]*((2/15)*Gs[o] - S[b]), o = uoutp[j*128+n];
// t2 = u1^T @ og; Zp = t2 @ u2; out[b,p] = Zp_flat[uinp[p]] + bias[p].
__global__ __launch_bounds__(1024)
void post_kernel(const float* __restrict__ G, const float* __restrict__ S,
                 const int* __restrict__ uoutp, const int* __restrict__ uinp,
                 const float* __restrict__ scale, const float* __restrict__ u1,
                 const float* __restrict__ u2, const float* __restrict__ bias,
                 float* __restrict__ out) {
    __shared__ alignas(16) u16 sU1[2][64 * 72];     // u1^T [i][j] stride 72
    __shared__ alignas(16) u16 sOG[2][128 * 72];    // og^T [n][j] stride 72; reused as t2 [i][k] stride 136
    __shared__ alignas(16) u16 sU2[2][128 * 136];   // u2^T [l][k] stride 136; reused as Zp f32[8192]
    const int tid = threadIdx.x, b = blockIdx.x;
    const int lane = tid & 63, w = tid >> 6;
    const int l15 = lane & 15, l4 = lane >> 4;
    const float Sb = S[b];

    #pragma unroll
    for (int it = 0; it < 4; ++it) {                // u1^T: u1[j*64+i] -> [i][j]
        int e = tid + it * 1024;
        u16 h, l; split_hl(u1[e], h, l);
        int idx = (e & 63) * 72 + (e >> 6);
        sU1[0][idx] = h; sU1[1][idx] = l;
    }
    #pragma unroll
    for (int it = 0; it < 16; ++it) {               // u2^T: u2[k*128+l] -> [l][k]
        int e = tid + it * 1024;
        u16 h, l; split_hl(u2[e], h, l);
        int idx = (e & 127) * 136 + (e >> 7);
        sU2[0][idx] = h; sU2[1][idx] = l;
    }
    int oo[8];
    #pragma unroll
    for (int it = 0; it < 8; ++it) oo[it] = uoutp[tid + it * 1024];
    #pragma unroll
    for (int it = 0; it < 8; ++it) {
        int o = oo[it];
        float gs = G[(size_t)b * OUT + o] + G[(size_t)(16 + b) * OUT + o]
                 + G[(size_t)(32 + b) * OUT + o] + G[(size_t)(48 + b) * OUT + o];
        float v = scale[o] * (gs * (2.0f / 15.0f) - Sb);
        u16 h, l; split_hl(v, h, l);
        int e = tid + it * 1024;
        int idx = (e & 127) * 72 + (e >> 7);        // og^T [n][j]
        sOG[0][idx] = h; sOG[1][idx] = l;
    }
    __syncthreads();

    // stage1: t2 = u1^T @ og  (M=64,N=128,K=64)
    const int nt = w & 7, mh = w >> 3;
    f32x4 acc0 = {0.f, 0.f, 0.f, 0.f}, acc1 = {0.f, 0.f, 0.f, 0.f};
    #pragma unroll
    for (int ks = 0; ks < 2; ++ks) {
        int boff = (nt * 16 + l15) * 72 + ks * 32 + l4 * 8;
        bf16x8 bh = ld8(&sOG[0][boff]), bl = ld8(&sOG[1][boff]);
        int a0 = (mh * 32 + l15) * 72 + ks * 32 + l4 * 8;
        int a1 = a0 + 16 * 72;
        bf16x8 ah0 = ld8(&sU1[0][a0]), al0 = ld8(&sU1[1][a0]);
        bf16x8 ah1 = ld8(&sU1[0][a1]), al1 = ld8(&sU1[1][a1]);
        acc0 = MFMA(ah0, bh, acc0); acc0 = MFMA(ah0, bl, acc0); acc0 = MFMA(al0, bh, acc0);
        acc1 = MFMA(ah1, bh, acc1); acc1 = MFMA(ah1, bl, acc1); acc1 = MFMA(al1, bh, acc1);
    }
    __syncthreads();
    u16* Thi = sOG[0]; u16* Tlo = sOG[1];           // t2 [i][k] stride 136
    #pragma unroll
    for (int m = 0; m < 2; ++m) {
        f32x4 a = m ? acc1 : acc0;
        #pragma unroll
        for (int r = 0; r < 4; ++r) {
            int i = mh * 32 + m * 16 + l4 * 4 + r;
            u16 h, l; split_hl(a[r], h, l);
            Thi[i * 136 + nt * 16 + l15] = h;
            Tlo[i * 136 + nt * 16 + l15] = l;
        }
    }
    __syncthreads();

    // stage2: Zp = t2 @ u2  (M=64,N=128,K=128)
    f32x4 z0 = {0.f, 0.f, 0.f, 0.f}, z1 = {0.f, 0.f, 0.f, 0.f};
    #pragma unroll
    for (int ks = 0; ks < 4; ++ks) {
        int boff = (nt * 16 + l15) * 136 + ks * 32 + l4 * 8;
        bf16x8 bh = ld8(&sU2[0][boff]), bl = ld8(&sU2[1][boff]);
        int a0 = (mh * 32 + l15) * 136 + ks * 32 + l4 * 8;
        int a1 = a0 + 16 * 136;
        bf16x8 ah0 = ld8(&Thi[a0]), al0 = ld8(&Tlo[a0]);
        bf16x8 ah1 = ld8(&Thi[a1]), al1 = ld8(&Tlo[a1]);
        z0 = MFMA(ah0, bh, z0); z0 = MFMA(ah0, bl, z0); z0 = MFMA(al0, bh, z0);
        z1 = MFMA(ah1, bh, z1); z1 = MFMA(ah1, bl, z1); z1 = MFMA(al1, bh, z1);
    }
    __syncthreads();                                // all waves done reading sU2
    float* Zp = reinterpret_cast<float*>(&sU2[0][0]);
    #pragma unroll
    for (int m = 0; m < 2; ++m) {
        f32x4 zz = m ? z1 : z0;
        #pragma unroll
        for (int r = 0; r < 4; ++r) {
            int i = mh * 32 + m * 16 + l4 * 4 + r;
            Zp[i * 128 + nt * 16 + l15] = zz[r];
        }
    }
    __syncthreads();
    #pragma unroll
    for (int it = 0; it < 8; ++it) {
        int p = tid + it * 1024;
        out[(size_t)b * OUT + p] = Zp[uinp[p]] + bias[p];
    }
}

extern "C" void kernel_launch(void* const* d_in, const int* in_sizes, int n_in,
                              void* d_out, int out_size, void* d_ws, size_t ws_size,
                              hipStream_t stream) {
    const float* x     = (const float*)d_in[0];
    const int*   qw    = (const int*)d_in[1];
    const float* scale = (const float*)d_in[2];
    const float* shw   = (const float*)d_in[3];
    const float* v1    = (const float*)d_in[4];
    const float* v2    = (const float*)d_in[5];
    const float* u1    = (const float*)d_in[6];
    const float* u2    = (const float*)d_in[7];
    const float* bias  = (const float*)d_in[8];
    const int* vinp  = (const int*)d_in[9];
    const int* voutp = (const int*)d_in[10];
    const int* uinp  = (const int*)d_in[11];
    const int* uoutp = (const int*)d_in[12];
    float* out = (float*)d_out;

    char* ws = (char*)d_ws;
    u16*   xt = (u16*)ws;                           // 256 KiB  [16][8192] bf16
    float* G  = (float*)(ws + (256 << 10));         // 2 MiB    [4][16][8192] f32
    float* S  = (float*)(ws + (2304 << 10));        // 64 B     [16] f32

    pre_kernel<<<16, 1024, 0, stream>>>(x, shw, vinp, voutp, v1, v2, xt, S);
    qgemm_kernel<<<dim3(128, 4), 256, 0, stream>>>(qw, xt, G);
    post_kernel<<<16, 1024, 0, stream>>>(G, S, uoutp, uinp, scale, u1, u2, bias, out);
}